// Round 9
// baseline (284.261 us; speedup 1.0000x reference)
//
#include <hip/hip_runtime.h>
#include <math.h>

#define B_ 2
#define S_ 2048
#define D_ 1024
#define H_ 16
#define ATTN_C 0.18033688011f   // log2(e)/8, folded into Q at proj store

typedef unsigned short ushort_t;
typedef __attribute__((ext_vector_type(8))) short short8;
typedef __attribute__((ext_vector_type(4))) short short4v;
typedef __attribute__((ext_vector_type(4))) float f32x4;
typedef __attribute__((ext_vector_type(2))) float f32x2;
typedef __attribute__((ext_vector_type(16))) float f32x16;
typedef __attribute__((ext_vector_type(4))) unsigned int uint4v;

#define MFMA(A, B, C) __builtin_amdgcn_mfma_f32_32x32x16_bf16((A), (B), (C), 0, 0, 0)
#define Z16 {0.f,0.f,0.f,0.f,0.f,0.f,0.f,0.f,0.f,0.f,0.f,0.f,0.f,0.f,0.f,0.f}

__device__ __forceinline__ ushort_t bf16rn(float x) {
    unsigned int u = __builtin_bit_cast(unsigned int, x);
    u += 0x7FFFu + ((u >> 16) & 1u);
    return (ushort_t)(u >> 16);
}
__device__ __forceinline__ float bf16tof(ushort_t h) {
    return __builtin_bit_cast(float, (unsigned int)h << 16);
}
__device__ __forceinline__ unsigned cvtpk(float lo, float hi) {
    unsigned r;
    asm("v_cvt_pk_bf16_f32 %0, %1, %2" : "=v"(r) : "v"(lo), "v"(hi));
    return r;
}
__device__ __forceinline__ void gload16(const void* g, void* l) {
    __builtin_amdgcn_global_load_lds(
        (const __attribute__((address_space(1))) unsigned int*)(unsigned long long)g,
        (__attribute__((address_space(3))) unsigned int*)(unsigned int)(unsigned long long)l,
        16, 0, 0);
}

// ---------------------------------------------------------------------------
// cvtx: X (q|k|v) fp32 -> hi bf16 plane (+ lo plane for q,k).
// ---------------------------------------------------------------------------
__global__ __launch_bounds__(256) void cvtx_kernel(
    const float* __restrict__ Xq, const float* __restrict__ Xk,
    const float* __restrict__ Xv,
    ushort_t* __restrict__ Xh, ushort_t* __restrict__ Xl)
{
    const int pr = blockIdx.y;
    const float* X = pr == 0 ? Xq : pr == 1 ? Xk : Xv;
    const size_t idx = ((size_t)blockIdx.x * 256 + threadIdx.x) * 8;
    f32x4 v0 = *(const f32x4*)(X + idx);
    f32x4 v1 = *(const f32x4*)(X + idx + 4);
    float f[8] = {v0.x, v0.y, v0.z, v0.w, v1.x, v1.y, v1.z, v1.w};
    short8 hi, lo;
#pragma unroll
    for (int i = 0; i < 8; ++i) {
        ushort_t hh = bf16rn(f[i]);
        hi[i] = (short)hh;
        lo[i] = (short)bf16rn(f[i] - bf16tof(hh));
    }
    const size_t base = (size_t)pr * 2 * S_ * D_;
    *(short8*)(Xh + base + idx) = hi;
    if (pr < 2) *(short8*)(Xl + base + idx) = lo;
}

// ---------------------------------------------------------------------------
// cvtw: W_q/W_k -> transposed hi/lo bf16 [h][n][1024]; W_v -> transposed hi.
// ---------------------------------------------------------------------------
__global__ __launch_bounds__(256) void cvtw_kernel(
    const float* __restrict__ Wq, const float* __restrict__ Wk,
    const float* __restrict__ Wv,
    ushort_t* __restrict__ wqh, ushort_t* __restrict__ wql,
    ushort_t* __restrict__ wkh, ushort_t* __restrict__ wkl,
    ushort_t* __restrict__ wvh)
{
    __shared__ float T[64][68];
    const int dt = blockIdx.x, h = blockIdx.y, mat = blockIdx.z;
    const int tid = threadIdx.x;
    const float* W = mat == 0 ? Wq : mat == 1 ? Wk : Wv;
    const float* Wb = W + ((size_t)h * 1024 + dt * 64) * 64;
#pragma unroll
    for (int u = 0; u < 4; ++u) {
        int idx = tid + u * 256;
        int d = idx >> 4, c4 = idx & 15;
        f32x4 v = *(const f32x4*)(Wb + (size_t)d * 64 + c4 * 4);
        T[d][c4 * 4 + 0] = v.x; T[d][c4 * 4 + 1] = v.y;
        T[d][c4 * 4 + 2] = v.z; T[d][c4 * 4 + 3] = v.w;
    }
    __syncthreads();
    ushort_t* oh = mat == 0 ? wqh : mat == 1 ? wkh : wvh;
    ushort_t* ol = mat == 0 ? wql : mat == 1 ? wkl : nullptr;
#pragma unroll
    for (int u = 0; u < 4; ++u) {
        int idx = tid + u * 256;
        int n = idx >> 4, c4 = idx & 15;
        float v0 = T[c4 * 4 + 0][n], v1 = T[c4 * 4 + 1][n];
        float v2 = T[c4 * 4 + 2][n], v3 = T[c4 * 4 + 3][n];
        ushort_t h0 = bf16rn(v0), h1 = bf16rn(v1), h2 = bf16rn(v2), h3 = bf16rn(v3);
        size_t off = ((size_t)h * 64 + n) * 1024 + dt * 64 + c4 * 4;
        short4v hv = {(short)h0, (short)h1, (short)h2, (short)h3};
        *(short4v*)(oh + off) = hv;
        if (ol) {
            short4v lv = {(short)bf16rn(v0 - bf16tof(h0)), (short)bf16rn(v1 - bf16tof(h1)),
                          (short)bf16rn(v2 - bf16tof(h2)), (short)bf16rn(v3 - bf16tof(h3))};
            *(short4v*)(ol + off) = lv;
        }
    }
}

__global__ __launch_bounds__(256) void cvtwo_kernel(
    const float* __restrict__ Wo, ushort_t* __restrict__ wob)
{
    size_t idx = (size_t)blockIdx.x * 256 + threadIdx.x;
    f32x4 v = *(const f32x4*)(Wo + idx * 4);
    short4v o = {(short)bf16rn(v.x), (short)bf16rn(v.y),
                 (short)bf16rn(v.z), (short)bf16rn(v.w)};
    *(short4v*)(wob + idx * 4) = o;
}

// ---------------------------------------------------------------------------
// proj: Out[b,h,s,n] = sum_d X[b,s,d] * W[h,d,n].  Q/K split-3 -> hi/lo rows;
// V single bf16 -> TRANSPOSED [bh][d][S].  Q pre-scaled by ATTN_C.
// grid (16, 8, pr*2+b), block 256.
// ---------------------------------------------------------------------------
__global__ __launch_bounds__(256, 2) void proj_kernel(
    const ushort_t* __restrict__ Xh, const ushort_t* __restrict__ Xl,
    const ushort_t* __restrict__ Wh_q, const ushort_t* __restrict__ Wl_q,
    const ushort_t* __restrict__ Wh_k, const ushort_t* __restrict__ Wl_k,
    const ushort_t* __restrict__ Wh_v,
    ushort_t* __restrict__ Oq_h, ushort_t* __restrict__ Oq_l,
    ushort_t* __restrict__ Ok_h, ushort_t* __restrict__ Ok_l,
    ushort_t* __restrict__ Ovt)
{
    __shared__ __align__(16) ushort_t Xs[128 * 128];
    __shared__ __align__(16) ushort_t Ws[128 * 128];
    const int tid = threadIdx.x;
    const int wv = tid >> 6, lane = tid & 63;
    const int lo32 = lane & 31, g = lane >> 5;
    const int wm = wv >> 1, wn = wv & 1;
    const int lrow = lane >> 4, lg = lane & 15;
    const int m0 = blockIdx.x * 128;
    const int n0 = blockIdx.y * 128;
    const int pr = blockIdx.z >> 1, b = blockIdx.z & 1;
    const bool split = (pr != 2);
    const ushort_t* Whp = pr == 0 ? Wh_q : pr == 1 ? Wh_k : Wh_v;
    const ushort_t* Wlp = pr == 0 ? Wl_q : pr == 1 ? Wl_k : Wh_v;
    const ushort_t* Xhb = Xh + ((size_t)(pr * 2 + b) * S_ + m0) * D_;
    const ushort_t* Xlb = Xl + ((size_t)(pr * 2 + b) * S_ + m0) * D_;
    f32x16 a00 = Z16, a01 = Z16, a10 = Z16, a11 = Z16;

    for (int d0 = 0; d0 < D_; d0 += 64) {
        __syncthreads();
#pragma unroll
        for (int u = 0; u < 8; ++u) {
            int row = u * 16 + wv * 4 + lrow;
            int gs = lg ^ (row & 15);
            int half = gs >> 3, c8 = gs & 7;
            const ushort_t* srcX = ((half && split) ? Xlb : Xhb) + (size_t)row * D_ + d0 + c8 * 8;
            gload16(srcX, (char*)Xs + (u * 16 + wv * 4) * 256);
            const ushort_t* srcW = ((half && split) ? Wlp : Whp) + (size_t)(n0 + row) * 1024 + d0 + c8 * 8;
            gload16(srcW, (char*)Ws + (u * 16 + wv * 4) * 256);
        }
        __syncthreads();
#pragma unroll
        for (int ks = 0; ks < 4; ++ks) {
            int coff = ks * 16 + g * 8;
            int r0 = wm * 64 + lo32, r1 = r0 + 32;
            int c0 = wn * 64 + lo32, c1 = c0 + 32;
            short8 a0h = *(const short8*)&Xs[(r0 * 128 + coff) ^ ((r0 & 15) << 3)];
            short8 a1h = *(const short8*)&Xs[(r1 * 128 + coff) ^ ((r1 & 15) << 3)];
            short8 b0h = *(const short8*)&Ws[(c0 * 128 + coff) ^ ((c0 & 15) << 3)];
            short8 b1h = *(const short8*)&Ws[(c1 * 128 + coff) ^ ((c1 & 15) << 3)];
            a00 = MFMA(a0h, b0h, a00);
            a01 = MFMA(a0h, b1h, a01);
            a10 = MFMA(a1h, b0h, a10);
            a11 = MFMA(a1h, b1h, a11);
            if (split) {
                short8 a0l = *(const short8*)&Xs[(r0 * 128 + 64 + coff) ^ ((r0 & 15) << 3)];
                short8 a1l = *(const short8*)&Xs[(r1 * 128 + 64 + coff) ^ ((r1 & 15) << 3)];
                short8 b0l = *(const short8*)&Ws[(c0 * 128 + 64 + coff) ^ ((c0 & 15) << 3)];
                short8 b1l = *(const short8*)&Ws[(c1 * 128 + 64 + coff) ^ ((c1 & 15) << 3)];
                a00 = MFMA(a0h, b0l, a00); a00 = MFMA(a0l, b0h, a00);
                a01 = MFMA(a0h, b1l, a01); a01 = MFMA(a0l, b1h, a01);
                a10 = MFMA(a1h, b0l, a10); a10 = MFMA(a1l, b0h, a10);
                a11 = MFMA(a1h, b1l, a11); a11 = MFMA(a1l, b1h, a11);
            }
        }
    }
    ushort_t* OH = pr == 0 ? Oq_h : pr == 1 ? Ok_h : Ovt;
    ushort_t* OL = pr == 0 ? Oq_l : pr == 1 ? Ok_l : Ovt;
    const bool qscale = (pr == 0);
#define PROJ_STORE(ACC, MT, NT)                                               \
    _Pragma("unroll")                                                         \
    for (int r = 0; r < 16; ++r) {                                            \
        int s_loc = m0 + wm * 64 + (MT) * 32 + (r & 3) + 8 * (r >> 2) + 4 * g;\
        int col = n0 + wn * 64 + (NT) * 32 + lo32;                            \
        int hh_ = col >> 6, nn = col & 63;                                    \
        float val = ACC[r];                                                   \
        if (qscale) val *= ATTN_C;                                            \
        if (split) {                                                          \
            size_t off = (((size_t)b * H_ + hh_) * S_ + s_loc) * 64 + nn;     \
            ushort_t hv = bf16rn(val);                                        \
            OH[off] = hv;                                                     \
            OL[off] = bf16rn(val - bf16tof(hv));                              \
        } else {                                                              \
            size_t offt = (((size_t)b * H_ + hh_) * 64 + nn) * S_ + s_loc;    \
            OH[offt] = bf16rn(val);                                           \
        }                                                                     \
    }
    PROJ_STORE(a00, 0, 0)
    PROJ_STORE(a01, 0, 1)
    PROJ_STORE(a10, 1, 0)
    PROJ_STORE(a11, 1, 1)
#undef PROJ_STORE
}

// ---------------------------------------------------------------------------
// attn: split-KV flash, 64 q/wave.  K-hi global->VGPR double-buffered; K-lo
// load issued SPECULATIVELY at chunk start (used only if refine fires).
// Aggressive exact skips: full-skip margin 64 log2-units (30 relevance +
// 34 = 14-sigma hi-error bound), post-refine softmax/PV skip margin 30
// (skipped terms < 2^-30 of running max -> invisible at fp32).
// V staged 256 kv per barrier pair (32KB LDS).
// grid (8 q-tiles of 256, 16 h, b*2+split), block 256.
// ---------------------------------------------------------------------------
__global__ __launch_bounds__(256, 2) void attn_kernel(
    const ushort_t* __restrict__ qh_h, const ushort_t* __restrict__ qh_l,
    const ushort_t* __restrict__ kh_h, const ushort_t* __restrict__ kh_l,
    const ushort_t* __restrict__ vt, ushort_t* __restrict__ Opart,
    float* __restrict__ Ml)
{
    __shared__ __align__(16) char smem[32768];   // 32KB Vt staging / epilogue
    ushort_t* Vt = (ushort_t*)smem;              // [64 d][256 kv] swizzled
    const int tid = threadIdx.x;
    const int wv = tid >> 6, lane = tid & 63;
    const int lo32 = lane & 31, g = lane >> 5;
    const int s0 = blockIdx.x * 256;
    const int h = blockIdx.y;
    const int b = blockIdx.z >> 1, sp = blockIdx.z & 1;
    const size_t bhs = ((size_t)b * H_ + h) * S_ * 64;

    short8 qfh[2][4], qfl[2][4];
#pragma unroll
    for (int c = 0; c < 2; ++c) {
        const ushort_t* Qrh = qh_h + bhs + (size_t)(s0 + wv * 64 + c * 32 + lo32) * 64;
        const ushort_t* Qrl = qh_l + bhs + (size_t)(s0 + wv * 64 + c * 32 + lo32) * 64;
#pragma unroll
        for (int ks = 0; ks < 4; ++ks) {
            qfh[c][ks] = *(const short8*)(Qrh + ks * 16 + g * 8);
            qfl[c][ks] = *(const short8*)(Qrl + ks * 16 + g * 8);
        }
    }
    const ushort_t* Kgh = kh_h + bhs;
    const ushort_t* Kgl = kh_l + bhs;
    const ushort_t* Vtg = vt + ((size_t)b * H_ + h) * 64 * S_;

    f32x16 o00 = Z16, o01 = Z16, o10 = Z16, o11 = Z16;
    float mrun0 = -3.0e38f, mrun1 = -3.0e38f;
    float lrun0 = 0.f, lrun1 = 0.f;
    const int kvbeg = sp * (S_ / 2);

#define MAX16(ST) fmaxf(fmaxf(fmaxf(fmaxf(ST[0], ST[1]), fmaxf(ST[2], ST[3])),   \
                              fmaxf(fmaxf(ST[4], ST[5]), fmaxf(ST[6], ST[7]))),  \
                        fmaxf(fmaxf(fmaxf(ST[8], ST[9]), fmaxf(ST[10], ST[11])), \
                              fmaxf(fmaxf(ST[12], ST[13]), fmaxf(ST[14], ST[15]))))

#define SOFTMAX_PV(ST, CME, MR, LR, OA, OB)                                   \
    {                                                                         \
        if (__any(CME > MR)) {                                                \
            float mnew = fmaxf(MR, CME);                                      \
            float corr = __builtin_amdgcn_exp2f(MR - mnew);                   \
            LR *= corr;                                                       \
            _Pragma("unroll")                                                 \
            for (int r = 0; r < 16; ++r) { OA[r] *= corr; OB[r] *= corr; }    \
            MR = mnew;                                                        \
        }                                                                     \
        float p[16], ls = 0.f;                                                \
        _Pragma("unroll")                                                     \
        for (int r = 0; r < 16; ++r) {                                        \
            p[r] = __builtin_amdgcn_exp2f(ST[r] - MR);                        \
            ls += p[r];                                                       \
        }                                                                     \
        LR += ls;                                                             \
        {                                                                     \
            unsigned w0 = cvtpk(p[0], p[1]), w1 = cvtpk(p[2], p[3]);          \
            unsigned w2 = cvtpk(p[4], p[5]), w3 = cvtpk(p[6], p[7]);          \
            asm("v_permlane32_swap_b32 %0, %1" : "+v"(w0), "+v"(w2));         \
            asm("v_permlane32_swap_b32 %0, %1" : "+v"(w1), "+v"(w3));         \
            uint4v pa = {w0, w1, w2, w3};                                     \
            short8 pf = __builtin_bit_cast(short8, pa);                       \
            OA = MFMA(vfa0, pf, OA);                                          \
            OB = MFMA(vfa1, pf, OB);                                          \
            w0 = cvtpk(p[8], p[9]);  w1 = cvtpk(p[10], p[11]);                \
            w2 = cvtpk(p[12], p[13]); w3 = cvtpk(p[14], p[15]);               \
            asm("v_permlane32_swap_b32 %0, %1" : "+v"(w0), "+v"(w2));         \
            asm("v_permlane32_swap_b32 %0, %1" : "+v"(w1), "+v"(w3));         \
            uint4v pb = {w0, w1, w2, w3};                                     \
            short8 pf2 = __builtin_bit_cast(short8, pb);                      \
            OA = MFMA(vfb0, pf2, OA);                                         \
            OB = MFMA(vfb1, pf2, OB);                                         \
        }                                                                     \
    }

#define LOADKHI(CI, DH)                                                       \
    {                                                                         \
        int cc = (CI) > 31 ? 31 : (CI);                                       \
        const ushort_t* pn = Kgh + (size_t)(kvbeg + cc * 32 + lo32) * 64 + g * 8; \
        DH[0] = *(const short8*)(pn);                                         \
        DH[1] = *(const short8*)(pn + 16);                                    \
        DH[2] = *(const short8*)(pn + 32);                                    \
        DH[3] = *(const short8*)(pn + 48);                                    \
    }

// Chunk: prefetch next hi; speculative lo load; 8 hi MFMAs; full-skip vote
// (margin 64); refine 16 MFMAs + post-refine vote (margin 30) + softmax/PV.
#define CHUNK_BODY(KH, KHN, CI)                                               \
    {                                                                         \
        LOADKHI((CI) + 1, KHN);                                               \
        const ushort_t* pl = Kgl + (size_t)(kvbeg + (CI) * 32 + lo32) * 64 + g * 8; \
        short8 kl0 = *(const short8*)(pl);                                    \
        short8 kl1 = *(const short8*)(pl + 16);                               \
        short8 kl2 = *(const short8*)(pl + 32);                               \
        short8 kl3 = *(const short8*)(pl + 48);                               \
        f32x16 st0 = Z16, st1 = Z16;                                          \
        st0 = MFMA(KH[0], qfh[0][0], st0); st1 = MFMA(KH[0], qfh[1][0], st1); \
        st0 = MFMA(KH[1], qfh[0][1], st0); st1 = MFMA(KH[1], qfh[1][1], st1); \
        st0 = MFMA(KH[2], qfh[0][2], st0); st1 = MFMA(KH[2], qfh[1][2], st1); \
        st0 = MFMA(KH[3], qfh[0][3], st0); st1 = MFMA(KH[3], qfh[1][3], st1); \
        float cm0 = MAX16(st0);                                               \
        float cm1 = MAX16(st1);                                               \
        cm0 = fmaxf(cm0, __shfl_xor(cm0, 32));                                \
        cm1 = fmaxf(cm1, __shfl_xor(cm1, 32));                                \
        const bool need0 = __any(cm0 > mrun0 - 64.f);                         \
        const bool need1 = __any(cm1 > mrun1 - 64.f);                         \
        if (need0 | need1) {                                                  \
            if (need0) {                                                      \
                st0 = MFMA(KH[0], qfl[0][0], st0); st0 = MFMA(kl0, qfh[0][0], st0); \
                st0 = MFMA(KH[1], qfl[0][1], st0); st0 = MFMA(kl1, qfh[0][1], st0); \
                st0 = MFMA(KH[2], qfl[0][2], st0); st0 = MFMA(kl2, qfh[0][2], st0); \
                st0 = MFMA(KH[3], qfl[0][3], st0); st0 = MFMA(kl3, qfh[0][3], st0); \
            }                                                                 \
            if (need1) {                                                      \
                st1 = MFMA(KH[0], qfl[1][0], st1); st1 = MFMA(kl0, qfh[1][0], st1); \
                st1 = MFMA(KH[1], qfl[1][1], st1); st1 = MFMA(kl1, qfh[1][1], st1); \
                st1 = MFMA(KH[2], qfl[1][2], st1); st1 = MFMA(kl2, qfh[1][2], st1); \
                st1 = MFMA(KH[3], qfl[1][3], st1); st1 = MFMA(kl3, qfh[1][3], st1); \
            }                                                                 \
            const int kvb = ((CI) & 7) * 32;                                  \
            const int vsw = (lo32 & 15) << 3;                                 \
            short8 vfa0 = *(const short8*)&Vt[(lo32 * 256 + kvb + g * 8) ^ vsw];        \
            short8 vfa1 = *(const short8*)&Vt[((lo32 + 32) * 256 + kvb + g * 8) ^ vsw]; \
            short8 vfb0 = *(const short8*)&Vt[(lo32 * 256 + kvb + 16 + g * 8) ^ vsw];   \
            short8 vfb1 = *(const short8*)&Vt[((lo32 + 32) * 256 + kvb + 16 + g * 8) ^ vsw]; \
            if (need0) {                                                      \
                float cme = MAX16(st0);                                       \
                cme = fmaxf(cme, __shfl_xor(cme, 32));                        \
                if (__any(cme > mrun0 - 30.f))                                \
                    SOFTMAX_PV(st0, cme, mrun0, lrun0, o00, o01)              \
            }                                                                 \
            if (need1) {                                                      \
                float cme = MAX16(st1);                                       \
                cme = fmaxf(cme, __shfl_xor(cme, 32));                        \
                if (__any(cme > mrun1 - 30.f))                                \
                    SOFTMAX_PV(st1, cme, mrun1, lrun1, o10, o11)              \
            }                                                                 \
        }                                                                     \
    }

    short8 ka_h[4], kb_h[4];
    LOADKHI(0, ka_h);
    int c = 0;
    for (int t = 0; t < 4; ++t) {
        const int kv0 = kvbeg + t * 256;
        __syncthreads();
        // V stage: 64 d-rows x 512B; 8 gload16/wave; source pre-swizzled so
        // read-side (idx ^ ((d&15)<<3)) lands on the right data.
#pragma unroll
        for (int u = 0; u < 8; ++u) {
            int rowb = u * 8 + wv * 2;
            int d = rowb + (lane >> 5);
            const ushort_t* src = Vtg + (size_t)d * S_ + kv0 + 8 * ((lane & 31) ^ (d & 15));
            gload16(src, (char*)Vt + rowb * 512);
        }
        __syncthreads();
        CHUNK_BODY(ka_h, kb_h, c + 0)
        CHUNK_BODY(kb_h, ka_h, c + 1)
        CHUNK_BODY(ka_h, kb_h, c + 2)
        CHUNK_BODY(kb_h, ka_h, c + 3)
        CHUNK_BODY(ka_h, kb_h, c + 4)
        CHUNK_BODY(kb_h, ka_h, c + 5)
        CHUNK_BODY(ka_h, kb_h, c + 6)
        CHUNK_BODY(kb_h, ka_h, c + 7)
        c += 8;
    }
#undef CHUNK_BODY
#undef LOADKHI
#undef SOFTMAX_PV
#undef MAX16

    lrun0 += __shfl_xor(lrun0, 32);
    lrun1 += __shfl_xor(lrun1, 32);
    __syncthreads();    // Vt dead; overlay epilogue scratch
    float* Oe = ((float*)smem) + wv * 2048;   // 8KB per-wave slice
    const size_t orowb = (size_t)sp * (B_ * H_ * S_) + ((size_t)b * H_ + h) * S_ + s0 + wv * 64;
    // set 0
#pragma unroll
    for (int r = 0; r < 16; ++r) {
        int dd = (r & 3) + 8 * (r >> 2) + 4 * g;
        int qsw = (lo32 & 7) << 2;
        Oe[(lo32 * 64 + dd) ^ qsw] = o00[r];
        Oe[(lo32 * 64 + 32 + dd) ^ qsw] = o01[r];
    }
#pragma unroll
    for (int rep = 0; rep < 8; ++rep) {
        int idx = lane + rep * 64;
        int qq = idx >> 4, d4 = idx & 15;
        f32x4 ov = *(const f32x4*)&Oe[(qq * 64 + d4 * 4) ^ ((qq & 7) << 2)];
        short4v pk4 = {(short)bf16rn(ov.x), (short)bf16rn(ov.y),
                       (short)bf16rn(ov.z), (short)bf16rn(ov.w)};
        *(short4v*)(Opart + (orowb + qq) * 64 + d4 * 4) = pk4;
    }
    if (g == 0) {
        f32x2 ml = {mrun0, lrun0};
        *(f32x2*)(Ml + (orowb + lo32) * 2) = ml;
    }
    __builtin_amdgcn_s_waitcnt(0);  // wave-private slice reuse ordering
    // set 1
#pragma unroll
    for (int r = 0; r < 16; ++r) {
        int dd = (r & 3) + 8 * (r >> 2) + 4 * g;
        int qsw = (lo32 & 7) << 2;
        Oe[(lo32 * 64 + dd) ^ qsw] = o10[r];
        Oe[(lo32 * 64 + 32 + dd) ^ qsw] = o11[r];
    }
#pragma unroll
    for (int rep = 0; rep < 8; ++rep) {
        int idx = lane + rep * 64;
        int qq = idx >> 4, d4 = idx & 15;
        f32x4 ov = *(const f32x4*)&Oe[(qq * 64 + d4 * 4) ^ ((qq & 7) << 2)];
        short4v pk4 = {(short)bf16rn(ov.x), (short)bf16rn(ov.y),
                       (short)bf16rn(ov.z), (short)bf16rn(ov.w)};
        *(short4v*)(Opart + (orowb + 32 + qq) * 64 + d4 * 4) = pk4;
    }
    if (g == 0) {
        f32x2 ml = {mrun1, lrun1};
        *(f32x2*)(Ml + (orowb + 32 + lo32) * 2) = ml;
    }
}

// ---------------------------------------------------------------------------
// merge: combine 2 KV-split partials -> ctx bf16 [B,S,D].
// ---------------------------------------------------------------------------
__global__ __launch_bounds__(256) void merge_kernel(
    const ushort_t* __restrict__ Opart, const float* __restrict__ Ml,
    ushort_t* __restrict__ ctxb)
{
    const int NROW = B_ * H_ * S_;
    int gidx = blockIdx.x * 256 + threadIdx.x;
    int row = gidx >> 3, d8 = (gidx & 7) * 8;
    f32x2 ml0 = *(const f32x2*)(Ml + (size_t)row * 2);
    f32x2 ml1 = *(const f32x2*)(Ml + ((size_t)NROW + row) * 2);
    float M = fmaxf(ml0.x, ml1.x);
    float w0 = __builtin_amdgcn_exp2f(ml0.x - M);
    float w1 = __builtin_amdgcn_exp2f(ml1.x - M);
    float inv = 1.f / (ml0.y * w0 + ml1.y * w1);
    w0 *= inv; w1 *= inv;
    short8 a = *(const short8*)(Opart + (size_t)row * 64 + d8);
    short8 c = *(const short8*)(Opart + ((size_t)NROW + row) * 64 + d8);
    short8 o;
#pragma unroll
    for (int i = 0; i < 8; ++i) {
        float f = bf16tof((ushort_t)a[i]) * w0 + bf16tof((ushort_t)c[i]) * w1;
        o[i] = (short)bf16rn(f);
    }
    int bb = row >> 15, hh = (row >> 11) & 15, s = row & 2047;
    *(short8*)(ctxb + ((size_t)bb * S_ + s) * D_ + hh * 64 + d8) = o;
}

// ---------------------------------------------------------------------------
// outproj: Out[m,n] = sum_k ctx[m,k]*Wo[n,k] + bo[n], bf16 MFMA.
// ---------------------------------------------------------------------------
__global__ __launch_bounds__(128, 2) void outproj_kernel(
    const ushort_t* __restrict__ ctxb, const ushort_t* __restrict__ wob,
    const float* __restrict__ bo, float* __restrict__ Out)
{
    __shared__ __align__(16) ushort_t Cs[128 * 128];
    __shared__ __align__(16) ushort_t Ws2[64 * 128];
    const int tid = threadIdx.x;
    const int wv = tid >> 6, lane = tid & 63;
    const int lo32 = lane & 31, g = lane >> 5;
    const int lrow = lane >> 4, lg = lane & 15;
    const int n0 = blockIdx.x * 64;
    const int m0 = blockIdx.y * 128;
    f32x16 a00 = Z16, a01 = Z16, a10 = Z16, a11 = Z16;
    for (int k0 = 0; k0 < D_; k0 += 128) {
        __syncthreads();
#pragma unroll
        for (int u = 0; u < 16; ++u) {
            int row = u * 8 + wv * 4 + lrow;
            int gs = lg ^ (row & 15);
            const ushort_t* src = ctxb + (size_t)(m0 + row) * D_ + k0 + gs * 8;
            gload16(src, (char*)Cs + (u * 8 + wv * 4) * 256);
        }
#pragma unroll
        for (int u = 0; u < 8; ++u) {
            int row = u * 8 + wv * 4 + lrow;
            int gs = lg ^ (row & 15);
            const ushort_t* src = wob + (size_t)(n0 + row) * D_ + k0 + gs * 8;
            gload16(src, (char*)Ws2 + (u * 8 + wv * 4) * 256);
        }
        __syncthreads();
#pragma unroll
        for (int ks = 0; ks < 8; ++ks) {
            int coff = ks * 16 + g * 8;
            int r0 = wv * 64 + lo32, r1 = r0 + 32;
            int n1 = lo32 + 32;
            short8 A0 = *(const short8*)&Cs[(r0 * 128 + coff) ^ ((r0 & 15) << 3)];
            short8 A1 = *(const short8*)&Cs[(r1 * 128 + coff) ^ ((r1 & 15) << 3)];
            short8 B0 = *(const short8*)&Ws2[(lo32 * 128 + coff) ^ ((lo32 & 15) << 3)];
            short8 B1 = *(const short8*)&Ws2[(n1 * 128 + coff) ^ ((n1 & 15) << 3)];
            a00 = MFMA(A0, B0, a00);
            a01 = MFMA(A0, B1, a01);
            a10 = MFMA(A1, B0, a10);
            a11 = MFMA(A1, B1, a11);
        }
    }
    float b0v = bo[n0 + lo32], b1v = bo[n0 + 32 + lo32];
#define OUT_STORE(ACC, MT, NT, BV)                                          \
    _Pragma("unroll")                                                       \
    for (int r = 0; r < 16; ++r) {                                          \
        int m = m0 + wv * 64 + (MT) * 32 + (r & 3) + 8 * (r >> 2) + 4 * g;  \
        int n = n0 + (NT) * 32 + lo32;                                      \
        Out[(size_t)m * D_ + n] = ACC[r] + (BV);                            \
    }
    OUT_STORE(a00, 0, 0, b0v)
    OUT_STORE(a01, 0, 1, b1v)
    OUT_STORE(a10, 1, 0, b0v)
    OUT_STORE(a11, 1, 1, b1v)
#undef OUT_STORE
}

// ---------------------------------------------------------------------------
extern "C" void kernel_launch(void* const* d_in, const int* in_sizes, int n_in,
                              void* d_out, int out_size, void* d_ws,
                              size_t ws_size, hipStream_t stream)
{
    const float* q = (const float*)d_in[0];
    const float* k = (const float*)d_in[1];
    const float* v = (const float*)d_in[2];
    const float* W_q = (const float*)d_in[3];
    const float* W_k = (const float*)d_in[4];
    const float* W_v = (const float*)d_in[5];
    const float* W_o = (const float*)d_in[6];
    const float* b_o = (const float*)d_in[7];
    float* out = (float*)d_out;

    ushort_t* wqt_h = (ushort_t*)d_ws;                 // 6 x 1M ushorts: weights
    ushort_t* wqt_l = wqt_h + (1 << 20);
    ushort_t* wkt_h = wqt_l + (1 << 20);
    ushort_t* wkt_l = wkt_h + (1 << 20);
    ushort_t* wvt_h = wkt_l + (1 << 20);
    ushort_t* wob   = wvt_h + (1 << 20);
    ushort_t* qh_h  = wob + (1 << 20);                 // 5 x 4M: proj outputs
    ushort_t* qh_l  = qh_h + (1 << 22);
    ushort_t* kh_h  = qh_l + (1 << 22);
    ushort_t* kh_l  = kh_h + (1 << 22);
    ushort_t* vtp   = kh_l + (1 << 22);                // V transposed [bh][64][S]
    ushort_t* Xh    = vtp + (1 << 22);                 // 12M: [3][2][S][D] hi
    ushort_t* Xl    = Xh + 3 * (1 << 22);              // 8M:  [2][2][S][D] lo (q,k)
    ushort_t* ctxb  = Xh;                              // alias: Xh dead after proj
    ushort_t* Opart = Xl;                              // alias: Xl dead after proj
    float*    Ml    = (float*)(Xl + 2 * (size_t)(B_ * H_ * S_) * 64);

    cvtx_kernel<<<dim3(2048, 3), 256, 0, stream>>>(q, k, v, Xh, Xl);
    cvtw_kernel<<<dim3(16, 16, 3), 256, 0, stream>>>(
        W_q, W_k, W_v, wqt_h, wqt_l, wkt_h, wkt_l, wvt_h);
    cvtwo_kernel<<<1024, 256, 0, stream>>>(W_o, wob);
    proj_kernel<<<dim3(16, 8, 6), 256, 0, stream>>>(
        Xh, Xl, wqt_h, wqt_l, wkt_h, wkt_l, wvt_h,
        qh_h, qh_l, kh_h, kh_l, vtp);
    attn_kernel<<<dim3(8, 16, 4), 256, 0, stream>>>(
        qh_h, qh_l, kh_h, kh_l, vtp, Opart, Ml);
    merge_kernel<<<2048, 256, 0, stream>>>(Opart, Ml, ctxb);
    outproj_kernel<<<dim3(16, 32), 128, 0, stream>>>(ctxb, wob, b_o, out);
}

// Round 10
// 218.119 us; speedup vs baseline: 1.3032x; 1.3032x over previous
//
#include <hip/hip_runtime.h>
#include <math.h>

#define B_ 2
#define S_ 2048
#define D_ 1024
#define H_ 16
#define ATTN_C 0.18033688011f   // log2(e)/8, folded into Q at proj store

typedef unsigned short ushort_t;
typedef __attribute__((ext_vector_type(8))) short short8;
typedef __attribute__((ext_vector_type(4))) short short4v;
typedef __attribute__((ext_vector_type(4))) float f32x4;
typedef __attribute__((ext_vector_type(2))) float f32x2;
typedef __attribute__((ext_vector_type(16))) float f32x16;
typedef __attribute__((ext_vector_type(4))) unsigned int uint4v;

#define MFMA(A, B, C) __builtin_amdgcn_mfma_f32_32x32x16_bf16((A), (B), (C), 0, 0, 0)
#define Z16 {0.f,0.f,0.f,0.f,0.f,0.f,0.f,0.f,0.f,0.f,0.f,0.f,0.f,0.f,0.f,0.f}

__device__ __forceinline__ ushort_t bf16rn(float x) {
    unsigned int u = __builtin_bit_cast(unsigned int, x);
    u += 0x7FFFu + ((u >> 16) & 1u);
    return (ushort_t)(u >> 16);
}
__device__ __forceinline__ float bf16tof(ushort_t h) {
    return __builtin_bit_cast(float, (unsigned int)h << 16);
}
__device__ __forceinline__ unsigned cvtpk(float lo, float hi) {
    unsigned r;
    asm("v_cvt_pk_bf16_f32 %0, %1, %2" : "=v"(r) : "v"(lo), "v"(hi));
    return r;
}
__device__ __forceinline__ void gload16(const void* g, void* l) {
    __builtin_amdgcn_global_load_lds(
        (const __attribute__((address_space(1))) unsigned int*)(unsigned long long)g,
        (__attribute__((address_space(3))) unsigned int*)(unsigned int)(unsigned long long)l,
        16, 0, 0);
}

// ---------------------------------------------------------------------------
// cvtx: X (q|k|v) fp32 -> hi bf16 plane (+ lo plane for q,k).
// ---------------------------------------------------------------------------
__global__ __launch_bounds__(256) void cvtx_kernel(
    const float* __restrict__ Xq, const float* __restrict__ Xk,
    const float* __restrict__ Xv,
    ushort_t* __restrict__ Xh, ushort_t* __restrict__ Xl)
{
    const int pr = blockIdx.y;
    const float* X = pr == 0 ? Xq : pr == 1 ? Xk : Xv;
    const size_t idx = ((size_t)blockIdx.x * 256 + threadIdx.x) * 8;
    f32x4 v0 = *(const f32x4*)(X + idx);
    f32x4 v1 = *(const f32x4*)(X + idx + 4);
    float f[8] = {v0.x, v0.y, v0.z, v0.w, v1.x, v1.y, v1.z, v1.w};
    short8 hi, lo;
#pragma unroll
    for (int i = 0; i < 8; ++i) {
        ushort_t hh = bf16rn(f[i]);
        hi[i] = (short)hh;
        lo[i] = (short)bf16rn(f[i] - bf16tof(hh));
    }
    const size_t base = (size_t)pr * 2 * S_ * D_;
    *(short8*)(Xh + base + idx) = hi;
    if (pr < 2) *(short8*)(Xl + base + idx) = lo;
}

// ---------------------------------------------------------------------------
// cvtw: W_q/W_k -> transposed hi/lo bf16 [h][n][1024]; W_v -> transposed hi.
// ---------------------------------------------------------------------------
__global__ __launch_bounds__(256) void cvtw_kernel(
    const float* __restrict__ Wq, const float* __restrict__ Wk,
    const float* __restrict__ Wv,
    ushort_t* __restrict__ wqh, ushort_t* __restrict__ wql,
    ushort_t* __restrict__ wkh, ushort_t* __restrict__ wkl,
    ushort_t* __restrict__ wvh)
{
    __shared__ float T[64][68];
    const int dt = blockIdx.x, h = blockIdx.y, mat = blockIdx.z;
    const int tid = threadIdx.x;
    const float* W = mat == 0 ? Wq : mat == 1 ? Wk : Wv;
    const float* Wb = W + ((size_t)h * 1024 + dt * 64) * 64;
#pragma unroll
    for (int u = 0; u < 4; ++u) {
        int idx = tid + u * 256;
        int d = idx >> 4, c4 = idx & 15;
        f32x4 v = *(const f32x4*)(Wb + (size_t)d * 64 + c4 * 4);
        T[d][c4 * 4 + 0] = v.x; T[d][c4 * 4 + 1] = v.y;
        T[d][c4 * 4 + 2] = v.z; T[d][c4 * 4 + 3] = v.w;
    }
    __syncthreads();
    ushort_t* oh = mat == 0 ? wqh : mat == 1 ? wkh : wvh;
    ushort_t* ol = mat == 0 ? wql : mat == 1 ? wkl : nullptr;
#pragma unroll
    for (int u = 0; u < 4; ++u) {
        int idx = tid + u * 256;
        int n = idx >> 4, c4 = idx & 15;
        float v0 = T[c4 * 4 + 0][n], v1 = T[c4 * 4 + 1][n];
        float v2 = T[c4 * 4 + 2][n], v3 = T[c4 * 4 + 3][n];
        ushort_t h0 = bf16rn(v0), h1 = bf16rn(v1), h2 = bf16rn(v2), h3 = bf16rn(v3);
        size_t off = ((size_t)h * 64 + n) * 1024 + dt * 64 + c4 * 4;
        short4v hv = {(short)h0, (short)h1, (short)h2, (short)h3};
        *(short4v*)(oh + off) = hv;
        if (ol) {
            short4v lv = {(short)bf16rn(v0 - bf16tof(h0)), (short)bf16rn(v1 - bf16tof(h1)),
                          (short)bf16rn(v2 - bf16tof(h2)), (short)bf16rn(v3 - bf16tof(h3))};
            *(short4v*)(ol + off) = lv;
        }
    }
}

__global__ __launch_bounds__(256) void cvtwo_kernel(
    const float* __restrict__ Wo, ushort_t* __restrict__ wob)
{
    size_t idx = (size_t)blockIdx.x * 256 + threadIdx.x;
    f32x4 v = *(const f32x4*)(Wo + idx * 4);
    short4v o = {(short)bf16rn(v.x), (short)bf16rn(v.y),
                 (short)bf16rn(v.z), (short)bf16rn(v.w)};
    *(short4v*)(wob + idx * 4) = o;
}

// ---------------------------------------------------------------------------
// proj: Out[b,h,s,n] = sum_d X[b,s,d] * W[h,d,n].  Q/K split-3 -> hi/lo rows;
// V single bf16 -> TRANSPOSED [bh][d][S] via LDS transpose (coalesced 256B
// row stores, not 2B scatter).  Q pre-scaled by ATTN_C.
// grid (16, 8, pr*2+b), block 256.
// ---------------------------------------------------------------------------
__global__ __launch_bounds__(256, 2) void proj_kernel(
    const ushort_t* __restrict__ Xh, const ushort_t* __restrict__ Xl,
    const ushort_t* __restrict__ Wh_q, const ushort_t* __restrict__ Wl_q,
    const ushort_t* __restrict__ Wh_k, const ushort_t* __restrict__ Wl_k,
    const ushort_t* __restrict__ Wh_v,
    ushort_t* __restrict__ Oq_h, ushort_t* __restrict__ Oq_l,
    ushort_t* __restrict__ Ok_h, ushort_t* __restrict__ Ok_l,
    ushort_t* __restrict__ Ovt)
{
    __shared__ __align__(16) ushort_t Xs[128 * 128];
    __shared__ __align__(16) ushort_t Ws[128 * 128];
    const int tid = threadIdx.x;
    const int wv = tid >> 6, lane = tid & 63;
    const int lo32 = lane & 31, g = lane >> 5;
    const int wm = wv >> 1, wn = wv & 1;
    const int lrow = lane >> 4, lg = lane & 15;
    const int m0 = blockIdx.x * 128;
    const int n0 = blockIdx.y * 128;
    const int pr = blockIdx.z >> 1, b = blockIdx.z & 1;
    const bool split = (pr != 2);
    const ushort_t* Whp = pr == 0 ? Wh_q : pr == 1 ? Wh_k : Wh_v;
    const ushort_t* Wlp = pr == 0 ? Wl_q : pr == 1 ? Wl_k : Wh_v;
    const ushort_t* Xhb = Xh + ((size_t)(pr * 2 + b) * S_ + m0) * D_;
    const ushort_t* Xlb = Xl + ((size_t)(pr * 2 + b) * S_ + m0) * D_;
    f32x16 a00 = Z16, a01 = Z16, a10 = Z16, a11 = Z16;

    for (int d0 = 0; d0 < D_; d0 += 64) {
        __syncthreads();
#pragma unroll
        for (int u = 0; u < 8; ++u) {
            int row = u * 16 + wv * 4 + lrow;
            int gs = lg ^ (row & 15);
            int half = gs >> 3, c8 = gs & 7;
            const ushort_t* srcX = ((half && split) ? Xlb : Xhb) + (size_t)row * D_ + d0 + c8 * 8;
            gload16(srcX, (char*)Xs + (u * 16 + wv * 4) * 256);
            const ushort_t* srcW = ((half && split) ? Wlp : Whp) + (size_t)(n0 + row) * 1024 + d0 + c8 * 8;
            gload16(srcW, (char*)Ws + (u * 16 + wv * 4) * 256);
        }
        __syncthreads();
#pragma unroll
        for (int ks = 0; ks < 4; ++ks) {
            int coff = ks * 16 + g * 8;
            int r0 = wm * 64 + lo32, r1 = r0 + 32;
            int c0 = wn * 64 + lo32, c1 = c0 + 32;
            short8 a0h = *(const short8*)&Xs[(r0 * 128 + coff) ^ ((r0 & 15) << 3)];
            short8 a1h = *(const short8*)&Xs[(r1 * 128 + coff) ^ ((r1 & 15) << 3)];
            short8 b0h = *(const short8*)&Ws[(c0 * 128 + coff) ^ ((c0 & 15) << 3)];
            short8 b1h = *(const short8*)&Ws[(c1 * 128 + coff) ^ ((c1 & 15) << 3)];
            a00 = MFMA(a0h, b0h, a00);
            a01 = MFMA(a0h, b1h, a01);
            a10 = MFMA(a1h, b0h, a10);
            a11 = MFMA(a1h, b1h, a11);
            if (split) {
                short8 a0l = *(const short8*)&Xs[(r0 * 128 + 64 + coff) ^ ((r0 & 15) << 3)];
                short8 a1l = *(const short8*)&Xs[(r1 * 128 + 64 + coff) ^ ((r1 & 15) << 3)];
                short8 b0l = *(const short8*)&Ws[(c0 * 128 + 64 + coff) ^ ((c0 & 15) << 3)];
                short8 b1l = *(const short8*)&Ws[(c1 * 128 + 64 + coff) ^ ((c1 & 15) << 3)];
                a00 = MFMA(a0h, b0l, a00); a00 = MFMA(a0l, b0h, a00);
                a01 = MFMA(a0h, b1l, a01); a01 = MFMA(a0l, b1h, a01);
                a10 = MFMA(a1h, b0l, a10); a10 = MFMA(a1l, b0h, a10);
                a11 = MFMA(a1h, b1l, a11); a11 = MFMA(a1l, b1h, a11);
            }
        }
    }
    if (split) {
        ushort_t* OH = pr == 0 ? Oq_h : Ok_h;
        ushort_t* OL = pr == 0 ? Oq_l : Ok_l;
        const bool qscale = (pr == 0);
#define PROJ_STORE(ACC, MT, NT)                                               \
    _Pragma("unroll")                                                         \
    for (int r = 0; r < 16; ++r) {                                            \
        int s_loc = m0 + wm * 64 + (MT) * 32 + (r & 3) + 8 * (r >> 2) + 4 * g;\
        int col = n0 + wn * 64 + (NT) * 32 + lo32;                            \
        int hh_ = col >> 6, nn = col & 63;                                    \
        float val = ACC[r];                                                   \
        if (qscale) val *= ATTN_C;                                            \
        size_t off = (((size_t)b * H_ + hh_) * S_ + s_loc) * 64 + nn;         \
        ushort_t hv = bf16rn(val);                                            \
        OH[off] = hv;                                                         \
        OL[off] = bf16rn(val - bf16tof(hv));                                  \
    }
        PROJ_STORE(a00, 0, 0)
        PROJ_STORE(a01, 0, 1)
        PROJ_STORE(a10, 1, 0)
        PROJ_STORE(a11, 1, 1)
#undef PROJ_STORE
    } else {
        // V: transpose 128x128 tile through LDS, write coalesced Vt rows.
        __syncthreads();           // all waves done reading Xs
        ushort_t* T = Xs;          // 128 cols x 128 s, swizzled
#define VT_PUT(ACC, MT, NT)                                                   \
    _Pragma("unroll")                                                         \
    for (int r = 0; r < 16; ++r) {                                            \
        int s_loc = wm * 64 + (MT) * 32 + (r & 3) + 8 * (r >> 2) + 4 * g;     \
        int col   = wn * 64 + (NT) * 32 + lo32;                               \
        T[col * 128 + (s_loc ^ ((col & 15) << 3))] = bf16rn(ACC[r]);          \
    }
        VT_PUT(a00, 0, 0)
        VT_PUT(a01, 0, 1)
        VT_PUT(a10, 1, 0)
        VT_PUT(a11, 1, 1)
#undef VT_PUT
        __syncthreads();
#pragma unroll
        for (int u = 0; u < 8; ++u) {
            int idx = tid + u * 256;
            int col = idx >> 4, ch = idx & 15;
            short8 v8 = *(const short8*)&T[col * 128 + ((ch * 8) ^ ((col & 15) << 3))];
            int gn = n0 + col;
            size_t orow = ((size_t)b * H_ + (gn >> 6)) * 64 + (gn & 63);
            *(short8*)(Ovt + orow * S_ + m0 + ch * 8) = v8;
        }
    }
}

// ---------------------------------------------------------------------------
// attn: split-KV flash, 64 q/wave (2 column-sets), KVBLK=128, K in LDS
// (hi/lo), two-phase QK with exact skips: phase-1 margin 64 (30 relevance +
// 34 hi-error bound), post-refine gate margin 30.  V staged via gload16 from
// pre-transposed Vt.  grid (8 q-tiles of 256, 16 h, b*2+split), block 256.
// ---------------------------------------------------------------------------
__global__ __launch_bounds__(256, 2) void attn_kernel(
    const ushort_t* __restrict__ qh_h, const ushort_t* __restrict__ qh_l,
    const ushort_t* __restrict__ kh_h, const ushort_t* __restrict__ kh_l,
    const ushort_t* __restrict__ vt, ushort_t* __restrict__ Opart,
    float* __restrict__ Ml)
{
    __shared__ __align__(16) char smem[49152];
    ushort_t* Ks = (ushort_t*)smem;              // 32KB [128][hi64|lo64] swz
    ushort_t* Vt = (ushort_t*)(smem + 32768);    // 16KB [64][128kv] swz
    const int tid = threadIdx.x;
    const int wv = tid >> 6, lane = tid & 63;
    const int lo32 = lane & 31, g = lane >> 5;
    const int lrow = lane >> 4, lg = lane & 15;
    const int s0 = blockIdx.x * 256;
    const int h = blockIdx.y;
    const int b = blockIdx.z >> 1, sp = blockIdx.z & 1;
    const size_t bhs = ((size_t)b * H_ + h) * S_ * 64;

    short8 qfh[2][4], qfl[2][4];
#pragma unroll
    for (int c = 0; c < 2; ++c) {
        const ushort_t* Qrh = qh_h + bhs + (size_t)(s0 + wv * 64 + c * 32 + lo32) * 64;
        const ushort_t* Qrl = qh_l + bhs + (size_t)(s0 + wv * 64 + c * 32 + lo32) * 64;
#pragma unroll
        for (int ks = 0; ks < 4; ++ks) {
            qfh[c][ks] = *(const short8*)(Qrh + ks * 16 + g * 8);
            qfl[c][ks] = *(const short8*)(Qrl + ks * 16 + g * 8);
        }
    }
    const ushort_t* Kgh = kh_h + bhs;
    const ushort_t* Kgl = kh_l + bhs;
    const ushort_t* Vtg = vt + ((size_t)b * H_ + h) * 64 * S_;

    f32x16 o00 = Z16, o01 = Z16, o10 = Z16, o11 = Z16;
    float mrun0 = -3.0e38f, mrun1 = -3.0e38f;
    float lrun0 = 0.f, lrun1 = 0.f;
    const int kvbeg = sp * (S_ / 2), kvend = kvbeg + (S_ / 2);

#define MAX16(ST)                                                             \
    fmaxf(fmaxf(fmaxf(fmaxf(ST[0], ST[1]), ST[2]),                            \
                fmaxf(fmaxf(ST[3], ST[4]), ST[5])),                           \
          fmaxf(fmaxf(fmaxf(ST[6], ST[7]), fmaxf(ST[8], ST[9])),              \
                fmaxf(fmaxf(fmaxf(ST[10], ST[11]), ST[12]),                   \
                      fmaxf(fmaxf(ST[13], ST[14]), ST[15]))))

    for (int kv0 = kvbeg; kv0 < kvend; kv0 += 128) {
        __syncthreads();
        // K stage: 128 rows x 256B, dest linear, source granule-swizzled
#pragma unroll
        for (int u = 0; u < 8; ++u) {
            int row = u * 16 + wv * 4 + lrow;
            int gs = lg ^ (row & 15);
            int half = gs >> 3, c8 = gs & 7;
            const ushort_t* src = (half ? Kgl : Kgh) + (size_t)(kv0 + row) * 64 + c8 * 8;
            gload16(src, (char*)Ks + (u * 16 + wv * 4) * 256);
        }
        // V stage: 64 d-rows x 256B from transposed global
#pragma unroll
        for (int u = 0; u < 4; ++u) {
            int d = u * 16 + wv * 4 + lrow;
            int gsrc = (lg & 8) | ((lg & 7) ^ (d & 7));
            const ushort_t* src = Vtg + (size_t)d * S_ + kv0 + gsrc * 8;
            gload16(src, (char*)Vt + (u * 16 + wv * 4) * 256);
        }
        __syncthreads();
#pragma unroll 1
        for (int ch = 0; ch < 4; ++ch) {
            const int kvb = ch * 32;
            const int krow = kvb + lo32;
            const int ksw = (krow & 15) << 3;
            short8 kfh0 = *(const short8*)&Ks[(krow * 128 + 0 * 16 + g * 8) ^ ksw];
            short8 kfh1 = *(const short8*)&Ks[(krow * 128 + 1 * 16 + g * 8) ^ ksw];
            short8 kfh2 = *(const short8*)&Ks[(krow * 128 + 2 * 16 + g * 8) ^ ksw];
            short8 kfh3 = *(const short8*)&Ks[(krow * 128 + 3 * 16 + g * 8) ^ ksw];
            f32x16 st0 = Z16, st1 = Z16;
            st0 = MFMA(kfh0, qfh[0][0], st0);  st1 = MFMA(kfh0, qfh[1][0], st1);
            st0 = MFMA(kfh1, qfh[0][1], st0);  st1 = MFMA(kfh1, qfh[1][1], st1);
            st0 = MFMA(kfh2, qfh[0][2], st0);  st1 = MFMA(kfh2, qfh[1][2], st1);
            st0 = MFMA(kfh3, qfh[0][3], st0);  st1 = MFMA(kfh3, qfh[1][3], st1);
            float cm0 = MAX16(st0);
            float cm1 = MAX16(st1);
            cm0 = fmaxf(cm0, __shfl_xor(cm0, 32));
            cm1 = fmaxf(cm1, __shfl_xor(cm1, 32));
            const bool need0 = __any(cm0 > mrun0 - 64.f);
            const bool need1 = __any(cm1 > mrun1 - 64.f);
            if (!need0 && !need1) continue;
            // refine: + kfh*qfl + kfl*qfh (exact split-3 scores)
            short8 kfl0 = *(const short8*)&Ks[(krow * 128 + 64 + 0 * 16 + g * 8) ^ ksw];
            short8 kfl1 = *(const short8*)&Ks[(krow * 128 + 64 + 1 * 16 + g * 8) ^ ksw];
            short8 kfl2 = *(const short8*)&Ks[(krow * 128 + 64 + 2 * 16 + g * 8) ^ ksw];
            short8 kfl3 = *(const short8*)&Ks[(krow * 128 + 64 + 3 * 16 + g * 8) ^ ksw];
            unsigned pw0[8], pw1[8];
            bool pv0 = false, pv1 = false;
            if (need0) {
                st0 = MFMA(kfh0, qfl[0][0], st0);  st0 = MFMA(kfl0, qfh[0][0], st0);
                st0 = MFMA(kfh1, qfl[0][1], st0);  st0 = MFMA(kfl1, qfh[0][1], st0);
                st0 = MFMA(kfh2, qfl[0][2], st0);  st0 = MFMA(kfl2, qfh[0][2], st0);
                st0 = MFMA(kfh3, qfl[0][3], st0);  st0 = MFMA(kfl3, qfh[0][3], st0);
                float cme = MAX16(st0);
                cme = fmaxf(cme, __shfl_xor(cme, 32));
                pv0 = __any(cme > mrun0 - 30.f);
                if (pv0) {
                    if (__any(cme > mrun0)) {
                        float mnew = fmaxf(mrun0, cme);
                        float corr = __builtin_amdgcn_exp2f(mrun0 - mnew);
                        lrun0 *= corr;
#pragma unroll
                        for (int r = 0; r < 16; ++r) { o00[r] *= corr; o01[r] *= corr; }
                        mrun0 = mnew;
                    }
                    float p[16], ls = 0.f;
#pragma unroll
                    for (int r = 0; r < 16; ++r) {
                        p[r] = __builtin_amdgcn_exp2f(st0[r] - mrun0);
                        ls += p[r];
                    }
                    lrun0 += ls;
#pragma unroll
                    for (int ks2 = 0; ks2 < 2; ++ks2) {
                        unsigned w0 = cvtpk(p[ks2 * 8 + 0], p[ks2 * 8 + 1]);
                        unsigned w1 = cvtpk(p[ks2 * 8 + 2], p[ks2 * 8 + 3]);
                        unsigned w2 = cvtpk(p[ks2 * 8 + 4], p[ks2 * 8 + 5]);
                        unsigned w3 = cvtpk(p[ks2 * 8 + 6], p[ks2 * 8 + 7]);
                        asm("v_permlane32_swap_b32 %0, %1" : "+v"(w0), "+v"(w2));
                        asm("v_permlane32_swap_b32 %0, %1" : "+v"(w1), "+v"(w3));
                        pw0[ks2 * 4 + 0] = w0; pw0[ks2 * 4 + 1] = w1;
                        pw0[ks2 * 4 + 2] = w2; pw0[ks2 * 4 + 3] = w3;
                    }
                }
            }
            if (need1) {
                st1 = MFMA(kfh0, qfl[1][0], st1);  st1 = MFMA(kfl0, qfh[1][0], st1);
                st1 = MFMA(kfh1, qfl[1][1], st1);  st1 = MFMA(kfl1, qfh[1][1], st1);
                st1 = MFMA(kfh2, qfl[1][2], st1);  st1 = MFMA(kfl2, qfh[1][2], st1);
                st1 = MFMA(kfh3, qfl[1][3], st1);  st1 = MFMA(kfl3, qfh[1][3], st1);
                float cme = MAX16(st1);
                cme = fmaxf(cme, __shfl_xor(cme, 32));
                pv1 = __any(cme > mrun1 - 30.f);
                if (pv1) {
                    if (__any(cme > mrun1)) {
                        float mnew = fmaxf(mrun1, cme);
                        float corr = __builtin_amdgcn_exp2f(mrun1 - mnew);
                        lrun1 *= corr;
#pragma unroll
                        for (int r = 0; r < 16; ++r) { o10[r] *= corr; o11[r] *= corr; }
                        mrun1 = mnew;
                    }
                    float p[16], ls = 0.f;
#pragma unroll
                    for (int r = 0; r < 16; ++r) {
                        p[r] = __builtin_amdgcn_exp2f(st1[r] - mrun1);
                        ls += p[r];
                    }
                    lrun1 += ls;
#pragma unroll
                    for (int ks2 = 0; ks2 < 2; ++ks2) {
                        unsigned w0 = cvtpk(p[ks2 * 8 + 0], p[ks2 * 8 + 1]);
                        unsigned w1 = cvtpk(p[ks2 * 8 + 2], p[ks2 * 8 + 3]);
                        unsigned w2 = cvtpk(p[ks2 * 8 + 4], p[ks2 * 8 + 5]);
                        unsigned w3 = cvtpk(p[ks2 * 8 + 6], p[ks2 * 8 + 7]);
                        asm("v_permlane32_swap_b32 %0, %1" : "+v"(w0), "+v"(w2));
                        asm("v_permlane32_swap_b32 %0, %1" : "+v"(w1), "+v"(w3));
                        pw1[ks2 * 4 + 0] = w0; pw1[ks2 * 4 + 1] = w1;
                        pw1[ks2 * 4 + 2] = w2; pw1[ks2 * 4 + 3] = w3;
                    }
                }
            }
            if (pv0 | pv1) {
#pragma unroll
                for (int ks2 = 0; ks2 < 2; ++ks2) {
                    int kvf = kvb + ks2 * 16 + g * 8;
                    int vsw = (lo32 & 7) << 3;
                    short8 vf0 = *(const short8*)&Vt[(lo32 * 128 + kvf) ^ vsw];
                    short8 vf1 = *(const short8*)&Vt[((lo32 + 32) * 128 + kvf) ^ vsw];
                    if (pv0) {
                        uint4v a = {pw0[ks2 * 4 + 0], pw0[ks2 * 4 + 1],
                                    pw0[ks2 * 4 + 2], pw0[ks2 * 4 + 3]};
                        short8 pf = __builtin_bit_cast(short8, a);
                        o00 = MFMA(vf0, pf, o00);
                        o01 = MFMA(vf1, pf, o01);
                    }
                    if (pv1) {
                        uint4v a = {pw1[ks2 * 4 + 0], pw1[ks2 * 4 + 1],
                                    pw1[ks2 * 4 + 2], pw1[ks2 * 4 + 3]};
                        short8 pf = __builtin_bit_cast(short8, a);
                        o10 = MFMA(vf0, pf, o10);
                        o11 = MFMA(vf1, pf, o11);
                    }
                }
            }
        }
    }
#undef MAX16

    lrun0 += __shfl_xor(lrun0, 32);
    lrun1 += __shfl_xor(lrun1, 32);
    __syncthreads();    // Ks/Vt dead; overlay epilogue scratch
    float* Oe = ((float*)smem) + wv * 2048;   // 8KB per-wave slice
    const size_t orowb = (size_t)sp * (B_ * H_ * S_) + ((size_t)b * H_ + h) * S_ + s0 + wv * 64;
    // set 0
#pragma unroll
    for (int r = 0; r < 16; ++r) {
        int dd = (r & 3) + 8 * (r >> 2) + 4 * g;
        int qsw = (lo32 & 7) << 2;
        Oe[(lo32 * 64 + dd) ^ qsw] = o00[r];
        Oe[(lo32 * 64 + 32 + dd) ^ qsw] = o01[r];
    }
#pragma unroll
    for (int rep = 0; rep < 8; ++rep) {
        int idx = lane + rep * 64;
        int qq = idx >> 4, d4 = idx & 15;
        f32x4 ov = *(const f32x4*)&Oe[(qq * 64 + d4 * 4) ^ ((qq & 7) << 2)];
        short4v pk4 = {(short)bf16rn(ov.x), (short)bf16rn(ov.y),
                       (short)bf16rn(ov.z), (short)bf16rn(ov.w)};
        *(short4v*)(Opart + (orowb + qq) * 64 + d4 * 4) = pk4;
    }
    if (g == 0) {
        f32x2 ml = {mrun0, lrun0};
        *(f32x2*)(Ml + (orowb + lo32) * 2) = ml;
    }
    __builtin_amdgcn_s_waitcnt(0);  // wave-private slice reuse ordering
    // set 1
#pragma unroll
    for (int r = 0; r < 16; ++r) {
        int dd = (r & 3) + 8 * (r >> 2) + 4 * g;
        int qsw = (lo32 & 7) << 2;
        Oe[(lo32 * 64 + dd) ^ qsw] = o10[r];
        Oe[(lo32 * 64 + 32 + dd) ^ qsw] = o11[r];
    }
#pragma unroll
    for (int rep = 0; rep < 8; ++rep) {
        int idx = lane + rep * 64;
        int qq = idx >> 4, d4 = idx & 15;
        f32x4 ov = *(const f32x4*)&Oe[(qq * 64 + d4 * 4) ^ ((qq & 7) << 2)];
        short4v pk4 = {(short)bf16rn(ov.x), (short)bf16rn(ov.y),
                       (short)bf16rn(ov.z), (short)bf16rn(ov.w)};
        *(short4v*)(Opart + (orowb + 32 + qq) * 64 + d4 * 4) = pk4;
    }
    if (g == 0) {
        f32x2 ml = {mrun1, lrun1};
        *(f32x2*)(Ml + (orowb + 32 + lo32) * 2) = ml;
    }
}

// ---------------------------------------------------------------------------
// merge: combine 2 KV-split partials -> ctx bf16 [B,S,D].
// ---------------------------------------------------------------------------
__global__ __launch_bounds__(256) void merge_kernel(
    const ushort_t* __restrict__ Opart, const float* __restrict__ Ml,
    ushort_t* __restrict__ ctxb)
{
    const int NROW = B_ * H_ * S_;
    int gidx = blockIdx.x * 256 + threadIdx.x;
    int row = gidx >> 3, d8 = (gidx & 7) * 8;
    f32x2 ml0 = *(const f32x2*)(Ml + (size_t)row * 2);
    f32x2 ml1 = *(const f32x2*)(Ml + ((size_t)NROW + row) * 2);
    float M = fmaxf(ml0.x, ml1.x);
    float w0 = __builtin_amdgcn_exp2f(ml0.x - M);
    float w1 = __builtin_amdgcn_exp2f(ml1.x - M);
    float inv = 1.f / (ml0.y * w0 + ml1.y * w1);
    w0 *= inv; w1 *= inv;
    short8 a = *(const short8*)(Opart + (size_t)row * 64 + d8);
    short8 c = *(const short8*)(Opart + ((size_t)NROW + row) * 64 + d8);
    short8 o;
#pragma unroll
    for (int i = 0; i < 8; ++i) {
        float f = bf16tof((ushort_t)a[i]) * w0 + bf16tof((ushort_t)c[i]) * w1;
        o[i] = (short)bf16rn(f);
    }
    int bb = row >> 15, hh = (row >> 11) & 15, s = row & 2047;
    *(short8*)(ctxb + ((size_t)bb * S_ + s) * D_ + hh * 64 + d8) = o;
}

// ---------------------------------------------------------------------------
// outproj: Out[m,n] = sum_k ctx[m,k]*Wo[n,k] + bo[n], bf16 MFMA.
// ---------------------------------------------------------------------------
__global__ __launch_bounds__(128, 2) void outproj_kernel(
    const ushort_t* __restrict__ ctxb, const ushort_t* __restrict__ wob,
    const float* __restrict__ bo, float* __restrict__ Out)
{
    __shared__ __align__(16) ushort_t Cs[128 * 128];
    __shared__ __align__(16) ushort_t Ws2[64 * 128];
    const int tid = threadIdx.x;
    const int wv = tid >> 6, lane = tid & 63;
    const int lo32 = lane & 31, g = lane >> 5;
    const int lrow = lane >> 4, lg = lane & 15;
    const int n0 = blockIdx.x * 64;
    const int m0 = blockIdx.y * 128;
    f32x16 a00 = Z16, a01 = Z16, a10 = Z16, a11 = Z16;
    for (int k0 = 0; k0 < D_; k0 += 128) {
        __syncthreads();
#pragma unroll
        for (int u = 0; u < 16; ++u) {
            int row = u * 8 + wv * 4 + lrow;
            int gs = lg ^ (row & 15);
            const ushort_t* src = ctxb + (size_t)(m0 + row) * D_ + k0 + gs * 8;
            gload16(src, (char*)Cs + (u * 8 + wv * 4) * 256);
        }
#pragma unroll
        for (int u = 0; u < 8; ++u) {
            int row = u * 8 + wv * 4 + lrow;
            int gs = lg ^ (row & 15);
            const ushort_t* src = wob + (size_t)(n0 + row) * D_ + k0 + gs * 8;
            gload16(src, (char*)Ws2 + (u * 8 + wv * 4) * 256);
        }
        __syncthreads();
#pragma unroll
        for (int ks = 0; ks < 8; ++ks) {
            int coff = ks * 16 + g * 8;
            int r0 = wv * 64 + lo32, r1 = r0 + 32;
            int n1 = lo32 + 32;
            short8 A0 = *(const short8*)&Cs[(r0 * 128 + coff) ^ ((r0 & 15) << 3)];
            short8 A1 = *(const short8*)&Cs[(r1 * 128 + coff) ^ ((r1 & 15) << 3)];
            short8 B0 = *(const short8*)&Ws2[(lo32 * 128 + coff) ^ ((lo32 & 15) << 3)];
            short8 B1 = *(const short8*)&Ws2[(n1 * 128 + coff) ^ ((n1 & 15) << 3)];
            a00 = MFMA(A0, B0, a00);
            a01 = MFMA(A0, B1, a01);
            a10 = MFMA(A1, B0, a10);
            a11 = MFMA(A1, B1, a11);
        }
    }
    float b0v = bo[n0 + lo32], b1v = bo[n0 + 32 + lo32];
#define OUT_STORE(ACC, MT, NT, BV)                                          \
    _Pragma("unroll")                                                       \
    for (int r = 0; r < 16; ++r) {                                          \
        int m = m0 + wv * 64 + (MT) * 32 + (r & 3) + 8 * (r >> 2) + 4 * g;  \
        int n = n0 + (NT) * 32 + lo32;                                      \
        Out[(size_t)m * D_ + n] = ACC[r] + (BV);                            \
    }
    OUT_STORE(a00, 0, 0, b0v)
    OUT_STORE(a01, 0, 1, b1v)
    OUT_STORE(a10, 1, 0, b0v)
    OUT_STORE(a11, 1, 1, b1v)
#undef OUT_STORE
}

// ---------------------------------------------------------------------------
extern "C" void kernel_launch(void* const* d_in, const int* in_sizes, int n_in,
                              void* d_out, int out_size, void* d_ws,
                              size_t ws_size, hipStream_t stream)
{
    const float* q = (const float*)d_in[0];
    const float* k = (const float*)d_in[1];
    const float* v = (const float*)d_in[2];
    const float* W_q = (const float*)d_in[3];
    const float* W_k = (const float*)d_in[4];
    const float* W_v = (const float*)d_in[5];
    const float* W_o = (const float*)d_in[6];
    const float* b_o = (const float*)d_in[7];
    float* out = (float*)d_out;

    ushort_t* wqt_h = (ushort_t*)d_ws;                 // 6 x 1M ushorts: weights
    ushort_t* wqt_l = wqt_h + (1 << 20);
    ushort_t* wkt_h = wqt_l + (1 << 20);
    ushort_t* wkt_l = wkt_h + (1 << 20);
    ushort_t* wvt_h = wkt_l + (1 << 20);
    ushort_t* wob   = wvt_h + (1 << 20);
    ushort_t* qh_h  = wob + (1 << 20);                 // 5 x 4M: proj outputs
    ushort_t* qh_l  = qh_h + (1 << 22);
    ushort_t* kh_h  = qh_l + (1 << 22);
    ushort_t* kh_l  = kh_h + (1 << 22);
    ushort_t* vtp   = kh_l + (1 << 22);                // V transposed [bh][64][S]
    ushort_t* Xh    = vtp + (1 << 22);                 // 12M: [3][2][S][D] hi
    ushort_t* Xl    = Xh + 3 * (1 << 22);              // 8M:  [2][2][S][D] lo (q,k)
    ushort_t* ctxb  = Xh;                              // alias: Xh dead after proj
    ushort_t* Opart = Xl;                              // alias: Xl dead after proj
    float*    Ml    = (float*)(Xl + 2 * (size_t)(B_ * H_ * S_) * 64);

    cvtx_kernel<<<dim3(2048, 3), 256, 0, stream>>>(q, k, v, Xh, Xl);
    cvtw_kernel<<<dim3(16, 16, 3), 256, 0, stream>>>(
        W_q, W_k, W_v, wqt_h, wqt_l, wkt_h, wkt_l, wvt_h);
    cvtwo_kernel<<<1024, 256, 0, stream>>>(W_o, wob);
    proj_kernel<<<dim3(16, 8, 6), 256, 0, stream>>>(
        Xh, Xl, wqt_h, wqt_l, wkt_h, wkt_l, wvt_h,
        qh_h, qh_l, kh_h, kh_l, vtp);
    attn_kernel<<<dim3(8, 16, 4), 256, 0, stream>>>(
        qh_h, qh_l, kh_h, kh_l, vtp, Opart, Ml);
    merge_kernel<<<2048, 256, 0, stream>>>(Opart, Ml, ctxb);
    outproj_kernel<<<dim3(16, 32), 128, 0, stream>>>(ctxb, wob, b_o, out);
}